// Round 6
// baseline (235.380 us; speedup 1.0000x reference)
//
#include <hip/hip_runtime.h>

#define TT 512
#define BB 1024
#define FF 16
#define HH 32
#define OO 8
#define CH 16   // timesteps per x-chunk staged through LDS

typedef _Float16 f16;
typedef f16 v2h __attribute__((ext_vector_type(2)));
typedef f16 v4h __attribute__((ext_vector_type(4)));

__device__ __forceinline__ float rcp_fast(float x) { return __builtin_amdgcn_rcpf(x); }
// inputs are PRE-SCALED by log2e (resp. 2*log2e), so plain exp2.
__device__ __forceinline__ float sigm2(float y) {
    return rcp_fast(1.0f + __builtin_amdgcn_exp2f(-y));
}
__device__ __forceinline__ float fdot2(v2h a, v2h b, float c) {
    return __builtin_amdgcn_fdot2(a, b, c, false);
}

#define PIN12(a,b,c,d,e,f,g,h,i,j,k,l) \
    asm volatile("" : "+v"(a),"+v"(b),"+v"(c),"+v"(d),"+v"(e),"+v"(f), \
                      "+v"(g),"+v"(h),"+v"(i),"+v"(j),"+v"(k),"+v"(l))

// One wave per block, one sequence per wave (2048 blocks, 2 waves/SIMD).
// k-split: lane (hi,kk) computes ALL 4 gate rows {kk,+32,+64,+96} over k-half
// hi. Weights/x/h in f16 pairs, dots via v_dot2_f32_f16 (2 MACs / 2 cyc vs
// pk_fma_f32's 2 MACs / 4 cyc) with f32 accumulation (two accums per gate
// for chain depth 6). Gate recombine: 4x shfl_xor(32). x staged through LDS
// as f16 in 16-step chunks; h exchanged as f16 through double-buffered LDS.
__global__ __launch_bounds__(64, 2)
void lstm_seq_kernel(const float* __restrict__ x,
                     const float* __restrict__ Wih_f, const float* __restrict__ Whh_f,
                     const float* __restrict__ b_f,
                     const float* __restrict__ Wih_b, const float* __restrict__ Whh_b,
                     const float* __restrict__ b_b,
                     float* __restrict__ hidden)
{
    const int bid  = blockIdx.x;          // 0..2047
    const int dir  = bid >> 10;           // 0 = fwd, 1 = bwd
    const int bb   = bid & (BB - 1);      // batch row
    const int lane = threadIdx.x;
    const int hi   = lane >> 5;           // k-half
    const int kk   = lane & 31;           // hidden index (row)

    const float* __restrict__ Wih  = dir ? Wih_b : Wih_f;
    const float* __restrict__ Whh  = dir ? Whh_b : Whh_f;
    const float* __restrict__ bias = dir ? b_b   : b_f;

    const float LOG2E = 1.4426950408889634f;
    const float L2E2  = 2.0f * LOG2E;

    // ---- stage this lane's weight slices as f16 pairs (pre-scaled) ----
    v2h wi[4][4];   // x-part: 8 f16 per gate
    v2h wh[4][8];   // h-part: 16 f16 per gate
    float pb[4];    // bias*scale (hi==0 only)
#pragma unroll
    for (int g = 0; g < 4; ++g) {
        const float sc = (g == 2) ? L2E2 : LOG2E;
        const int row = kk + g * HH;
        const float4* pi = (const float4*)(Wih + row * FF + hi * 8);
        float4 a = pi[0], b2 = pi[1];
        wi[g][0] = (v2h){(f16)(a.x * sc), (f16)(a.y * sc)};
        wi[g][1] = (v2h){(f16)(a.z * sc), (f16)(a.w * sc)};
        wi[g][2] = (v2h){(f16)(b2.x * sc), (f16)(b2.y * sc)};
        wi[g][3] = (v2h){(f16)(b2.z * sc), (f16)(b2.w * sc)};
        const float4* ph = (const float4*)(Whh + row * HH + hi * 16);
        float4 c0 = ph[0], c1 = ph[1], c2 = ph[2], c3 = ph[3];
        wh[g][0] = (v2h){(f16)(c0.x * sc), (f16)(c0.y * sc)};
        wh[g][1] = (v2h){(f16)(c0.z * sc), (f16)(c0.w * sc)};
        wh[g][2] = (v2h){(f16)(c1.x * sc), (f16)(c1.y * sc)};
        wh[g][3] = (v2h){(f16)(c1.z * sc), (f16)(c1.w * sc)};
        wh[g][4] = (v2h){(f16)(c2.x * sc), (f16)(c2.y * sc)};
        wh[g][5] = (v2h){(f16)(c2.z * sc), (f16)(c2.w * sc)};
        wh[g][6] = (v2h){(f16)(c3.x * sc), (f16)(c3.y * sc)};
        wh[g][7] = (v2h){(f16)(c3.z * sc), (f16)(c3.w * sc)};
        pb[g] = hi ? 0.0f : bias[row] * sc;
    }

    __shared__ __align__(8) f16 xsb[2 * CH * FF];  // 1 KB: two x chunks (f16)
    __shared__ __align__(8) f16 hsb[2 * HH];       // double-buffered h (f16)

    // ---- x chunk staging: lane (sl,wl) covers step sl, quarter wl ----
    const int sl = lane >> 2;
    const int wl = lane & 3;
    const int t0 = dir ? (TT - 1 - sl) : sl;
    const float* xp = x + (size_t)t0 * (BB * FF) + (size_t)bb * FF + wl * 4;
    const ptrdiff_t dstep = (dir ? -(ptrdiff_t)CH : (ptrdiff_t)CH) * (BB * FF);

    {
        float4 f0 = *(const float4*)xp;
        *(v4h*)(xsb + sl * FF + wl * 4) =
            (v4h){(f16)f0.x, (f16)f0.y, (f16)f0.z, (f16)f0.w};
    }
    xp += dstep;
    hsb[lane] = (f16)0.0f;   // zeros both h buffers (2*HH = 64)
    __syncthreads();

    float c = 0.0f, h = 0.0f;

    for (int ci = 0; ci < TT / CH; ++ci) {
        const bool more = (ci + 1 < TT / CH);
        float4 nf;
        if (more) { nf = *(const float4*)xp; xp += dstep; }   // 16 steps early

        const int xbase = (ci & 1) * (CH * FF) + hi * 8;
#pragma unroll
        for (int tt = 0; tt < CH; ++tt) {
            // keep all weight pairs pinned in arch VGPRs every iteration
            PIN12(wi[0][0], wi[0][1], wi[0][2], wi[0][3],
                  wi[1][0], wi[1][1], wi[1][2], wi[1][3],
                  wi[2][0], wi[2][1], wi[2][2], wi[2][3]);
            PIN12(wi[3][0], wi[3][1], wi[3][2], wi[3][3],
                  wh[0][0], wh[0][1], wh[0][2], wh[0][3],
                  wh[0][4], wh[0][5], wh[0][6], wh[0][7]);
            PIN12(wh[1][0], wh[1][1], wh[1][2], wh[1][3],
                  wh[1][4], wh[1][5], wh[1][6], wh[1][7],
                  wh[2][0], wh[2][1], wh[2][2], wh[2][3]);
            PIN12(wh[2][4], wh[2][5], wh[2][6], wh[2][7],
                  wh[3][0], wh[3][1], wh[3][2], wh[3][3],
                  wh[3][4], wh[3][5], wh[3][6], wh[3][7]);

            const v2h* xv = (const v2h*)(xsb + xbase + tt * FF);
            const v2h x0 = xv[0], x1 = xv[1], x2 = xv[2], x3 = xv[3];
            const v2h* hv = (const v2h*)(hsb + (tt & 1) * HH + hi * 16);
            const v2h h0 = hv[0], h1 = hv[1], h2 = hv[2], h3 = hv[3];
            const v2h h4 = hv[4], h5 = hv[5], h6 = hv[6], h7 = hv[7];

            // two accumulators per gate (chain depth 6), interleaved for ILP
            float A0 = fdot2(x0, wi[0][0], pb[0]);
            float A1 = fdot2(x0, wi[1][0], pb[1]);
            float A2 = fdot2(x0, wi[2][0], pb[2]);
            float A3 = fdot2(x0, wi[3][0], pb[3]);
            float B0 = fdot2(x2, wi[0][2], 0.0f);
            float B1 = fdot2(x2, wi[1][2], 0.0f);
            float B2 = fdot2(x2, wi[2][2], 0.0f);
            float B3 = fdot2(x2, wi[3][2], 0.0f);
            A0 = fdot2(x1, wi[0][1], A0);
            A1 = fdot2(x1, wi[1][1], A1);
            A2 = fdot2(x1, wi[2][1], A2);
            A3 = fdot2(x1, wi[3][1], A3);
            B0 = fdot2(x3, wi[0][3], B0);
            B1 = fdot2(x3, wi[1][3], B1);
            B2 = fdot2(x3, wi[2][3], B2);
            B3 = fdot2(x3, wi[3][3], B3);
            A0 = fdot2(h0, wh[0][0], A0);
            A1 = fdot2(h0, wh[1][0], A1);
            A2 = fdot2(h0, wh[2][0], A2);
            A3 = fdot2(h0, wh[3][0], A3);
            B0 = fdot2(h4, wh[0][4], B0);
            B1 = fdot2(h4, wh[1][4], B1);
            B2 = fdot2(h4, wh[2][4], B2);
            B3 = fdot2(h4, wh[3][4], B3);
            A0 = fdot2(h1, wh[0][1], A0);
            A1 = fdot2(h1, wh[1][1], A1);
            A2 = fdot2(h1, wh[2][1], A2);
            A3 = fdot2(h1, wh[3][1], A3);
            B0 = fdot2(h5, wh[0][5], B0);
            B1 = fdot2(h5, wh[1][5], B1);
            B2 = fdot2(h5, wh[2][5], B2);
            B3 = fdot2(h5, wh[3][5], B3);
            A0 = fdot2(h2, wh[0][2], A0);
            A1 = fdot2(h2, wh[1][2], A1);
            A2 = fdot2(h2, wh[2][2], A2);
            A3 = fdot2(h2, wh[3][2], A3);
            B0 = fdot2(h6, wh[0][6], B0);
            B1 = fdot2(h6, wh[1][6], B1);
            B2 = fdot2(h6, wh[2][6], B2);
            B3 = fdot2(h6, wh[3][6], B3);
            A0 = fdot2(h3, wh[0][3], A0);
            A1 = fdot2(h3, wh[1][3], A1);
            A2 = fdot2(h3, wh[2][3], A2);
            A3 = fdot2(h3, wh[3][3], A3);
            B0 = fdot2(h7, wh[0][7], B0);
            B1 = fdot2(h7, wh[1][7], B1);
            B2 = fdot2(h7, wh[2][7], B2);
            B3 = fdot2(h7, wh[3][7], B3);

            float g0 = A0 + B0;         // pre-scaled by log2e
            float g1 = A1 + B1;
            float g2 = A2 + B2;         // pre-scaled by 2*log2e
            float g3 = A3 + B3;
            g0 += __shfl_xor(g0, 32);   // i
            g1 += __shfl_xor(g1, 32);   // f
            g2 += __shfl_xor(g2, 32);   // g
            g3 += __shfl_xor(g3, 32);   // o

            const float si = sigm2(g0);
            const float sf = sigm2(g1);
            const float tg = fmaf(2.0f, sigm2(g2), -1.0f);   // tanh(g)
            const float so = sigm2(g3);
            c = fmaf(sf, c, si * tg);
            const float th = fmaf(2.0f, sigm2(L2E2 * c), -1.0f);  // tanh(c)
            h = so * th;

            if (tt == CH - 1 && more) {
                *(v4h*)(xsb + ((ci + 1) & 1) * (CH * FF) + sl * FF + wl * 4) =
                    (v4h){(f16)nf.x, (f16)nf.y, (f16)nf.z, (f16)nf.w};
            }
            hsb[((tt & 1) ^ 1) * HH + kk] = (f16)h;   // dup write both halves
            __syncthreads();
        }
    }

    if (hi == 0) hidden[(size_t)bb * 64 + dir * HH + kk] = h;
}

// FC1 + per-block partial of FC2. Grid: 32 blocks x 256 threads.
__global__ __launch_bounds__(256)
void fc_partial_kernel(const float* __restrict__ hidden,
                       const float* __restrict__ Wfh, const float* __restrict__ bfh,
                       const float* __restrict__ Wfo,
                       float* __restrict__ partials)
{
    __shared__ float wsh[OO * 64];
    const int tid = threadIdx.x;
    for (int i = tid; i < OO * 64; i += 256) wsh[i] = Wfh[i];
    __syncthreads();

    const int r   = tid >> 3;
    const int o   = tid & 7;
    const int row = blockIdx.x * 32 + r;

    const float* hrow = hidden + (size_t)row * 64;
    float acc = bfh[o];
#pragma unroll
    for (int j = 0; j < 64; ++j) acc += hrow[j] * wsh[o * 64 + j];

    const int fidx = blockIdx.x * 256 + tid;

    float pv[OO];
#pragma unroll
    for (int o2 = 0; o2 < OO; ++o2) pv[o2] = Wfo[(size_t)o2 * (BB * OO) + fidx] * acc;

    __shared__ float red[4][OO];
#pragma unroll
    for (int o2 = 0; o2 < OO; ++o2) {
        float v = pv[o2];
        for (int off = 32; off > 0; off >>= 1) v += __shfl_down(v, off);
        if ((tid & 63) == 0) red[tid >> 6][o2] = v;
    }
    __syncthreads();
    if (tid < OO) {
        partials[blockIdx.x * OO + tid] =
            red[0][tid] + red[1][tid] + red[2][tid] + red[3][tid];
    }
}

__global__ void finalize_kernel(const float* __restrict__ partials,
                                const float* __restrict__ bfo,
                                float* __restrict__ out)
{
    __shared__ float s[OO];
    const int tid = threadIdx.x;
    if (tid < OO) {
        float acc = bfo[tid];
        for (int b = 0; b < 32; ++b) acc += partials[b * OO + tid];
        s[tid] = acc;
    }
    __syncthreads();
    if (tid == 0) {
        float m = s[0];
        for (int i = 1; i < OO; ++i) m = fmaxf(m, s[i]);
        float e[OO], sum = 0.0f;
        for (int i = 0; i < OO; ++i) { e[i] = expf(s[i] - m); sum += e[i]; }
        for (int i = 0; i < OO; ++i) out[i] = e[i] / sum;
    }
}

extern "C" void kernel_launch(void* const* d_in, const int* in_sizes, int n_in,
                              void* d_out, int out_size, void* d_ws, size_t ws_size,
                              hipStream_t stream) {
    const float* x     = (const float*)d_in[0];
    const float* Wih_f = (const float*)d_in[1];
    const float* Whh_f = (const float*)d_in[2];
    const float* b_f   = (const float*)d_in[3];
    const float* Wih_b = (const float*)d_in[4];
    const float* Whh_b = (const float*)d_in[5];
    const float* b_b   = (const float*)d_in[6];
    const float* Wfh   = (const float*)d_in[7];
    const float* bfh   = (const float*)d_in[8];
    const float* Wfo   = (const float*)d_in[9];
    const float* bfo   = (const float*)d_in[10];

    float* hidden   = (float*)d_ws;
    float* partials = hidden + (size_t)BB * 64;

    lstm_seq_kernel<<<2 * BB, 64, 0, stream>>>(x, Wih_f, Whh_f, b_f,
                                               Wih_b, Whh_b, b_b, hidden);
    fc_partial_kernel<<<32, 256, 0, stream>>>(hidden, Wfh, bfh, Wfo, partials);
    finalize_kernel<<<1, 64, 0, stream>>>(partials, bfo, (float*)d_out);
}

// Round 7
// 218.501 us; speedup vs baseline: 1.0772x; 1.0772x over previous
//
#include <hip/hip_runtime.h>

#define TT 512
#define BB 1024
#define FF 16
#define HH 32
#define OO 8
#define CH 16   // timesteps per x-chunk staged through LDS

typedef _Float16 f16;
typedef f16 v2h __attribute__((ext_vector_type(2)));
typedef f16 v4h __attribute__((ext_vector_type(4)));

__device__ __forceinline__ float rcp_fast(float x) { return __builtin_amdgcn_rcpf(x); }
// inputs are PRE-SCALED by log2e (resp. 2*log2e), so plain exp2.
__device__ __forceinline__ float sigm2(float y) {
    return rcp_fast(1.0f + __builtin_amdgcn_exp2f(-y));
}
__device__ __forceinline__ float fdot2(v2h a, v2h b, float c) {
    return __builtin_amdgcn_fdot2(a, b, c, false);
}
__device__ __forceinline__ v2h i2h(int s) { return __builtin_bit_cast(v2h, s); }

// One wave per block, one sequence per wave (2048 blocks, 2 waves/SIMD).
// ROW-SPLIT FULL-K layout: lane (hi,kk) owns gate rows r0 = kk+hi*32
// (i or f) and r1 = r0+64 (g or o) over ALL 48 input dims -> gates complete
// in-lane, NO cross-lane gate reduction. h is broadcast through SGPRs:
// after the update, h pairs are packed to f16x2 (cvt_pkrtz + 1 DPP) and
// pulled by 16 v_readlane into SGPRs that feed v_dot2 src0 directly.
// => ZERO per-step LDS/DS ops on the critical chain except one shfl_xor
// (p1 <-> sf exchange). x staged through LDS in 16-step f16 chunks.
__global__ __launch_bounds__(64, 2)
void lstm_seq_kernel(const float* __restrict__ x,
                     const float* __restrict__ Wih_f, const float* __restrict__ Whh_f,
                     const float* __restrict__ b_f,
                     const float* __restrict__ Wih_b, const float* __restrict__ Whh_b,
                     const float* __restrict__ b_b,
                     float* __restrict__ hidden)
{
    const int bid  = blockIdx.x;          // 0..2047
    const int dir  = bid >> 10;           // 0 = fwd, 1 = bwd
    const int bb   = bid & (BB - 1);      // batch row
    const int lane = threadIdx.x;
    const int hi   = lane >> 5;           // 0: rows {i,g}   1: rows {f,o}
    const int kk   = lane & 31;           // hidden unit

    const float* __restrict__ Wih  = dir ? Wih_b : Wih_f;
    const float* __restrict__ Whh  = dir ? Whh_b : Whh_f;
    const float* __restrict__ bias = dir ? b_b   : b_f;

    const float LOG2E = 1.4426950408889634f;
    const float L2E2  = 2.0f * LOG2E;

    const int r0 = kk + hi * HH;      // i (hi=0) or f (hi=1): sigmoid
    const int r1 = r0 + 2 * HH;       // g (hi=0, tanh) or o (hi=1, sigmoid)
    const float sc0 = LOG2E;
    const float sc1 = hi ? LOG2E : L2E2;
    // post-activation for r1: tanh = 2*sigm2-1 (hi=0), sigmoid (hi=1)
    const float pm = hi ? 1.0f : 2.0f;
    const float pa = hi ? 0.0f : -1.0f;

    // ---- stage this lane's 2 full rows as f16 pairs (pre-scaled) ----
    v2h w0x[FF / 2], w1x[FF / 2];     // x-part: 8 pairs per row
    v2h w0h[HH / 2], w1h[HH / 2];     // h-part: 16 pairs per row
#pragma unroll
    for (int q = 0; q < FF / 4; ++q) {
        float4 a = ((const float4*)(Wih + r0 * FF))[q];
        w0x[2*q]   = (v2h){(f16)(a.x * sc0), (f16)(a.y * sc0)};
        w0x[2*q+1] = (v2h){(f16)(a.z * sc0), (f16)(a.w * sc0)};
        float4 b2 = ((const float4*)(Wih + r1 * FF))[q];
        w1x[2*q]   = (v2h){(f16)(b2.x * sc1), (f16)(b2.y * sc1)};
        w1x[2*q+1] = (v2h){(f16)(b2.z * sc1), (f16)(b2.w * sc1)};
    }
#pragma unroll
    for (int q = 0; q < HH / 4; ++q) {
        float4 a = ((const float4*)(Whh + r0 * HH))[q];
        w0h[2*q]   = (v2h){(f16)(a.x * sc0), (f16)(a.y * sc0)};
        w0h[2*q+1] = (v2h){(f16)(a.z * sc0), (f16)(a.w * sc0)};
        float4 b2 = ((const float4*)(Whh + r1 * HH))[q];
        w1h[2*q]   = (v2h){(f16)(b2.x * sc1), (f16)(b2.y * sc1)};
        w1h[2*q+1] = (v2h){(f16)(b2.z * sc1), (f16)(b2.w * sc1)};
    }
    const float pb0 = bias[r0] * sc0;
    const float pb1 = bias[r1] * sc1;

    __shared__ __align__(8) f16 xsb[2 * CH * FF];  // 1 KB: two x chunks

    // ---- x chunk staging: lane (sl,wl) covers step sl, quarter wl ----
    const int sl = lane >> 2;
    const int wl = lane & 3;
    const int t0 = dir ? (TT - 1 - sl) : sl;
    const float* xp = x + (size_t)t0 * (BB * FF) + (size_t)bb * FF + wl * 4;
    const ptrdiff_t dstep = (dir ? -(ptrdiff_t)CH : (ptrdiff_t)CH) * (BB * FF);

    {
        float4 f0 = *(const float4*)xp;
        *(v4h*)(xsb + sl * FF + wl * 4) =
            (v4h){(f16)f0.x, (f16)f0.y, (f16)f0.z, (f16)f0.w};
    }
    xp += dstep;
    __syncthreads();

    float c = 0.0f, h = 0.0f;
    // h broadcast state: 16 packed f16 pairs, uniform (SGPRs)
    int hs[HH / 2];
#pragma unroll
    for (int m = 0; m < HH / 2; ++m) hs[m] = 0;

    for (int ci = 0; ci < TT / CH; ++ci) {
        const bool more = (ci + 1 < TT / CH);
        float4 nf;
        if (more) { nf = *(const float4*)xp; xp += dstep; }   // 16 steps early

        const int xbase = (ci & 1) * (CH * FF);
#pragma unroll
        for (int tt = 0; tt < CH; ++tt) {
            // x slice: uniform address -> LDS broadcast, conflict-free
            const v2h* xv = (const v2h*)(xsb + xbase + tt * FF);
            v2h xr[8];
#pragma unroll
            for (int j = 0; j < 8; ++j) xr[j] = xv[j];

            // three independent 8-deep chains per row:
            // A = bias + x-dots (no h dependency: overlaps the h-gather)
            float A0 = fdot2(xr[0], w0x[0], pb0);
            float A1 = fdot2(xr[0], w1x[0], pb1);
#pragma unroll
            for (int j = 1; j < 8; ++j) {
                A0 = fdot2(xr[j], w0x[j], A0);
                A1 = fdot2(xr[j], w1x[j], A1);
            }
            // B = h pairs 0..7, C = h pairs 8..15 (SGPR operands)
            float B0 = fdot2(i2h(hs[0]), w0h[0], 0.0f);
            float B1 = fdot2(i2h(hs[0]), w1h[0], 0.0f);
            float C0 = fdot2(i2h(hs[8]), w0h[8], 0.0f);
            float C1 = fdot2(i2h(hs[8]), w1h[8], 0.0f);
#pragma unroll
            for (int j = 1; j < 8; ++j) {
                B0 = fdot2(i2h(hs[j]),     w0h[j],     B0);
                B1 = fdot2(i2h(hs[j]),     w1h[j],     B1);
                C0 = fdot2(i2h(hs[8 + j]), w0h[8 + j], C0);
                C1 = fdot2(i2h(hs[8 + j]), w1h[8 + j], C1);
            }

            const float g0 = A0 + (B0 + C0);   // i (lo) / f (hi), pre-scaled
            const float g1 = A1 + (B1 + C1);   // g (lo) / o (hi), pre-scaled

            const float s0 = sigm2(g0);                 // si (lo) / sf (hi)
            const float s1 = fmaf(sigm2(g1), pm, pa);   // tg (lo) / so (hi)
            const float prod = s0 * s1;                 // p1 (lo) / unused (hi)

            // one exchange: lo sends p1, hi sends sf
            const float sendv = hi ? s0 : prod;
            const float recv  = __shfl_xor(sendv, 32);
            const float sf = hi ? s0   : recv;
            const float p1 = hi ? recv : prod;

            c = fmaf(sf, c, p1);
            const float th = fmaf(2.0f, sigm2(L2E2 * c), -1.0f);  // tanh(c)
            h = s1 * th;   // valid on hi lanes (so*th); lo lanes garbage, unused

            // gather h into SGPRs: pack pairs (DPP xor-1 within quad), then
            // 16 readlanes from even hi-lanes 32,34,...,62
            const int hn = __builtin_amdgcn_mov_dpp(__float_as_int(h),
                                                    0xB1, 0xF, 0xF, true);
            auto pk = __builtin_amdgcn_cvt_pkrtz(h, __int_as_float(hn));
            const int pki = __builtin_bit_cast(int, pk);
#pragma unroll
            for (int m = 0; m < HH / 2; ++m)
                hs[m] = __builtin_amdgcn_readlane(pki, 32 + 2 * m);

            // stage next x chunk into the other buffer (in-order DS per wave)
            if (tt == CH - 1 && more) {
                *(v4h*)(xsb + ((ci + 1) & 1) * (CH * FF) + sl * FF + wl * 4) =
                    (v4h){(f16)nf.x, (f16)nf.y, (f16)nf.z, (f16)nf.w};
            }
        }
        __syncthreads();   // once per 16 steps (1-wave block: just a waitcnt)
    }

    // hidden[b][0:32] = h_fwd, hidden[b][32:64] = h_bwd (h lives on hi lanes)
    if (hi) hidden[(size_t)bb * 64 + dir * HH + kk] = h;
}

// FC1 + per-block partial of FC2. Grid: 32 blocks x 256 threads.
__global__ __launch_bounds__(256)
void fc_partial_kernel(const float* __restrict__ hidden,
                       const float* __restrict__ Wfh, const float* __restrict__ bfh,
                       const float* __restrict__ Wfo,
                       float* __restrict__ partials)
{
    __shared__ float wsh[OO * 64];
    const int tid = threadIdx.x;
    for (int i = tid; i < OO * 64; i += 256) wsh[i] = Wfh[i];
    __syncthreads();

    const int r   = tid >> 3;
    const int o   = tid & 7;
    const int row = blockIdx.x * 32 + r;

    const float* hrow = hidden + (size_t)row * 64;
    float acc = bfh[o];
#pragma unroll
    for (int j = 0; j < 64; ++j) acc += hrow[j] * wsh[o * 64 + j];

    const int fidx = blockIdx.x * 256 + tid;

    float pv[OO];
#pragma unroll
    for (int o2 = 0; o2 < OO; ++o2) pv[o2] = Wfo[(size_t)o2 * (BB * OO) + fidx] * acc;

    __shared__ float red[4][OO];
#pragma unroll
    for (int o2 = 0; o2 < OO; ++o2) {
        float v = pv[o2];
        for (int off = 32; off > 0; off >>= 1) v += __shfl_down(v, off);
        if ((tid & 63) == 0) red[tid >> 6][o2] = v;
    }
    __syncthreads();
    if (tid < OO) {
        partials[blockIdx.x * OO + tid] =
            red[0][tid] + red[1][tid] + red[2][tid] + red[3][tid];
    }
}

__global__ void finalize_kernel(const float* __restrict__ partials,
                                const float* __restrict__ bfo,
                                float* __restrict__ out)
{
    __shared__ float s[OO];
    const int tid = threadIdx.x;
    if (tid < OO) {
        float acc = bfo[tid];
        for (int b = 0; b < 32; ++b) acc += partials[b * OO + tid];
        s[tid] = acc;
    }
    __syncthreads();
    if (tid == 0) {
        float m = s[0];
        for (int i = 1; i < OO; ++i) m = fmaxf(m, s[i]);
        float e[OO], sum = 0.0f;
        for (int i = 0; i < OO; ++i) { e[i] = expf(s[i] - m); sum += e[i]; }
        for (int i = 0; i < OO; ++i) out[i] = e[i] / sum;
    }
}

extern "C" void kernel_launch(void* const* d_in, const int* in_sizes, int n_in,
                              void* d_out, int out_size, void* d_ws, size_t ws_size,
                              hipStream_t stream) {
    const float* x     = (const float*)d_in[0];
    const float* Wih_f = (const float*)d_in[1];
    const float* Whh_f = (const float*)d_in[2];
    const float* b_f   = (const float*)d_in[3];
    const float* Wih_b = (const float*)d_in[4];
    const float* Whh_b = (const float*)d_in[5];
    const float* b_b   = (const float*)d_in[6];
    const float* Wfh   = (const float*)d_in[7];
    const float* bfh   = (const float*)d_in[8];
    const float* Wfo   = (const float*)d_in[9];
    const float* bfo   = (const float*)d_in[10];

    float* hidden   = (float*)d_ws;
    float* partials = hidden + (size_t)BB * 64;

    lstm_seq_kernel<<<2 * BB, 64, 0, stream>>>(x, Wih_f, Whh_f, b_f,
                                               Wih_b, Whh_b, b_b, hidden);
    fc_partial_kernel<<<32, 256, 0, stream>>>(hidden, Wfh, bfh, Wfo, partials);
    finalize_kernel<<<1, 64, 0, stream>>>(partials, bfo, (float*)d_out);
}

// Round 8
// 200.295 us; speedup vs baseline: 1.1752x; 1.0909x over previous
//
#include <hip/hip_runtime.h>

#define TT 512
#define BB 1024
#define FF 16
#define HH 32
#define OO 8
#define CH 16             // timesteps per x-chunk
#define NC (TT / CH)      // 32 chunks
#define NG 128            // gate rows (4*HH)

typedef _Float16 f16;
typedef f16 v2h __attribute__((ext_vector_type(2)));
typedef f16 v4h __attribute__((ext_vector_type(4)));
typedef f16 v8h __attribute__((ext_vector_type(8)));
typedef float f32x4 __attribute__((ext_vector_type(4)));

__device__ __forceinline__ float rcp_fast(float x) { return __builtin_amdgcn_rcpf(x); }
// inputs PRE-SCALED by log2e (resp. 2*log2e) -> plain exp2
__device__ __forceinline__ float sigm2(float y) {
    return rcp_fast(1.0f + __builtin_amdgcn_exp2f(-y));
}
__device__ __forceinline__ float fdot2(v2h a, v2h b, float c) {
    return __builtin_amdgcn_fdot2(a, b, c, false);
}
__device__ __forceinline__ v2h i2h(int s) { return __builtin_bit_cast(v2h, s); }

// One wave per block, one sequence per wave (2048 blocks, 2 waves/SIMD).
// Row-split full-k: lane (hi,kk) owns gate rows r0=kk+hi*32 (i/f) and
// r1=r0+64 (g/o). h-part: 32 v_dot2 per step vs SGPR-broadcast h.
// x-part: OFF the per-step path -> per 16-step chunk one MFMA batch
// Gx = Wih_sc(128x16) * Xchunk^T(16x16) via 8x mfma_f32_16x16x32_f16
// (K padded 16->32, zero upper lanes), scattered to LDS gxb[step][gate];
// in-loop just 2x ds_read_b32. c/h maintained on hi lanes only.
__global__ __launch_bounds__(64, 2)
void lstm_seq_kernel(const float* __restrict__ x,
                     const float* __restrict__ Wih_f, const float* __restrict__ Whh_f,
                     const float* __restrict__ b_f,
                     const float* __restrict__ Wih_b, const float* __restrict__ Whh_b,
                     const float* __restrict__ b_b,
                     float* __restrict__ hidden)
{
    const int bid  = blockIdx.x;          // 0..2047
    const int dir  = bid >> 10;           // 0 = fwd, 1 = bwd
    const int bb   = bid & (BB - 1);      // batch row
    const int lane = threadIdx.x;
    const int hi   = lane >> 5;           // 0: rows {i,g}   1: rows {f,o}
    const int kk   = lane & 31;

    const float* __restrict__ Wih  = dir ? Wih_b : Wih_f;
    const float* __restrict__ Whh  = dir ? Whh_b : Whh_f;
    const float* __restrict__ bias = dir ? b_b   : b_f;

    const float LOG2E = 1.4426950408889634f;
    const float L2E2  = 2.0f * LOG2E;

    const int r0 = kk + hi * HH;      // i (hi=0) / f (hi=1)
    const int r1 = r0 + 2 * HH;       // g (hi=0) / o (hi=1)
    const float sc0 = LOG2E;
    const float sc1 = hi ? LOG2E : L2E2;
    const float pm = hi ? 1.0f : 2.0f;
    const float pa = hi ? 0.0f : -1.0f;

    // ---- recurrent weights: 2 rows x 16 h-pairs, f16, pre-scaled ----
    v2h w0h[HH / 2], w1h[HH / 2];
#pragma unroll
    for (int q = 0; q < HH / 4; ++q) {
        float4 a = ((const float4*)(Whh + r0 * HH))[q];
        w0h[2*q]   = (v2h){(f16)(a.x * sc0), (f16)(a.y * sc0)};
        w0h[2*q+1] = (v2h){(f16)(a.z * sc0), (f16)(a.w * sc0)};
        float4 b2 = ((const float4*)(Whh + r1 * HH))[q];
        w1h[2*q]   = (v2h){(f16)(b2.x * sc1), (f16)(b2.y * sc1)};
        w1h[2*q+1] = (v2h){(f16)(b2.z * sc1), (f16)(b2.w * sc1)};
    }
    const float pb0 = bias[r0] * sc0;
    const float pb1 = bias[r1] * sc1;

    // ---- MFMA A-fragments: Wih pre-scaled, 8 tiles of 16 gate rows ----
    // A row = lane&15 -> gate = 16T+(lane&15); k = (lane>>4)*8+j, zero k>=16
    v8h aw[8];
#pragma unroll
    for (int T = 0; T < 8; ++T) {
        v8h t = {(f16)0,(f16)0,(f16)0,(f16)0,(f16)0,(f16)0,(f16)0,(f16)0};
        if (lane < 32) {
            const int gate = T * 16 + (lane & 15);
            const float sc = (gate >= 64 && gate < 96) ? L2E2 : LOG2E;
            const float* wrow = Wih + gate * FF + (lane >> 4) * 8;
#pragma unroll
            for (int j = 0; j < 8; ++j) t[j] = (f16)(wrow[j] * sc);
        }
        aw[T] = t;
    }

    __shared__ __align__(16) f16   xsb[2 * CH * FF];   // 1 KB: x chunks (f16)
    __shared__ __align__(16) float gxb[2 * CH * NG];   // 16 KB: x-gates (f32)

    // ---- x chunk staging: lane (sl,wl) covers step sl, quarter wl ----
    const int sl = lane >> 2;
    const int wl = lane & 3;
    const int t0 = dir ? (TT - 1 - sl) : sl;
    const float* xp = x + (size_t)t0 * (BB * FF) + (size_t)bb * FF + wl * 4;
    const ptrdiff_t dstep = (dir ? -(ptrdiff_t)CH : (ptrdiff_t)CH) * (BB * FF);

    // prologue: stage chunk 0, compute gx[0], prefetch chunk 1
    {
        float4 f0 = *(const float4*)xp;
        *(v4h*)(xsb + sl * FF + wl * 4) =
            (v4h){(f16)f0.x, (f16)f0.y, (f16)f0.z, (f16)f0.w};
    }
    xp += dstep;
    __syncthreads();
    {
        v8h bx = {(f16)0,(f16)0,(f16)0,(f16)0,(f16)0,(f16)0,(f16)0,(f16)0};
        if (lane < 32)
            bx = *(const v8h*)(xsb + (lane & 15) * FF + (lane >> 4) * 8);
        float* gw = gxb + (lane & 15) * NG + (lane >> 4) * 4;
#pragma unroll
        for (int T = 0; T < 8; ++T) {
            f32x4 acc = __builtin_amdgcn_mfma_f32_16x16x32_f16(
                aw[T], bx, (f32x4){0.f, 0.f, 0.f, 0.f}, 0, 0, 0);
            *(f32x4*)(gw + T * 16) = acc;
        }
    }
    float4 nf = *(const float4*)xp;   // chunk 1
    xp += dstep;
    __syncthreads();

    float c = 0.0f, h = 0.0f;
    int hs[HH / 2];                   // packed f16 h-pairs (wave-uniform)
#pragma unroll
    for (int m = 0; m < HH / 2; ++m) hs[m] = 0;

    for (int ci = 0; ci < NC; ++ci) {
        const int bufc = ci & 1;
        if (ci + 1 < NC) {
            const int bufn = bufc ^ 1;
            // stage chunk ci+1 and compute its gx (off the critical chain)
            *(v4h*)(xsb + bufn * (CH * FF) + sl * FF + wl * 4) =
                (v4h){(f16)nf.x, (f16)nf.y, (f16)nf.z, (f16)nf.w};
            v8h bx = {(f16)0,(f16)0,(f16)0,(f16)0,(f16)0,(f16)0,(f16)0,(f16)0};
            if (lane < 32)
                bx = *(const v8h*)(xsb + bufn * (CH * FF) + (lane & 15) * FF + (lane >> 4) * 8);
            float* gw = gxb + bufn * (CH * NG) + (lane & 15) * NG + (lane >> 4) * 4;
#pragma unroll
            for (int T = 0; T < 8; ++T) {
                f32x4 acc = __builtin_amdgcn_mfma_f32_16x16x32_f16(
                    aw[T], bx, (f32x4){0.f, 0.f, 0.f, 0.f}, 0, 0, 0);
                *(f32x4*)(gw + T * 16) = acc;
            }
            if (ci + 2 < NC) { nf = *(const float4*)xp; xp += dstep; }
        }

        const float* gxc = gxb + bufc * (CH * NG);
#pragma unroll
        for (int tt = 0; tt < CH; ++tt) {
            // x-gate contributions (ready in LDS since chunk start)
            const float gx0 = gxc[tt * NG + r0];
            const float gx1 = gxc[tt * NG + r1];

            // recurrent dots: two 8-deep chains per row
            float B0 = fdot2(i2h(hs[0]), w0h[0], pb0);
            float B1 = fdot2(i2h(hs[0]), w1h[0], pb1);
            float C0 = fdot2(i2h(hs[8]), w0h[8], gx0);
            float C1 = fdot2(i2h(hs[8]), w1h[8], gx1);
#pragma unroll
            for (int j = 1; j < 8; ++j) {
                B0 = fdot2(i2h(hs[j]),     w0h[j],     B0);
                B1 = fdot2(i2h(hs[j]),     w1h[j],     B1);
                C0 = fdot2(i2h(hs[8 + j]), w0h[8 + j], C0);
                C1 = fdot2(i2h(hs[8 + j]), w1h[8 + j], C1);
            }
            const float g0 = B0 + C0;   // i (lo) / f (hi)
            const float g1 = B1 + C1;   // g (lo) / o (hi)

            const float s0 = sigm2(g0);                // si (lo) / sf (hi)
            const float s1 = fmaf(sigm2(g1), pm, pa);  // tg (lo) / so (hi)
            const float prod = s0 * s1;                // si*tg on lo lanes

            // hi lanes receive lo's si*tg; lo lanes' c/h are garbage (unused)
            const float recv = __shfl_xor(prod, 32);
            c = fmaf(s0, c, recv);                      // hi: sf*c + si*tg
            const float th = fmaf(2.0f, sigm2(L2E2 * c), -1.0f);
            h = s1 * th;                                // hi: so*tanh(c)

            // gather h (hi lanes) into wave-uniform SGPRs for next step
            const int hn = __builtin_amdgcn_mov_dpp(__float_as_int(h),
                                                    0xB1, 0xF, 0xF, true);
            auto pk = __builtin_amdgcn_cvt_pkrtz(h, __int_as_float(hn));
            const int pki = __builtin_bit_cast(int, pk);
#pragma unroll
            for (int m = 0; m < HH / 2; ++m)
                hs[m] = __builtin_amdgcn_readlane(pki, 32 + 2 * m);
        }
        __syncthreads();   // 1-wave block: orders LDS buffers across chunks
    }

    if (hi) hidden[(size_t)bb * 64 + dir * HH + kk] = h;
}

// FC1 + per-block partial of FC2. Grid: 32 blocks x 256 threads.
__global__ __launch_bounds__(256)
void fc_partial_kernel(const float* __restrict__ hidden,
                       const float* __restrict__ Wfh, const float* __restrict__ bfh,
                       const float* __restrict__ Wfo,
                       float* __restrict__ partials)
{
    __shared__ float wsh[OO * 64];
    const int tid = threadIdx.x;
    for (int i = tid; i < OO * 64; i += 256) wsh[i] = Wfh[i];
    __syncthreads();

    const int r   = tid >> 3;
    const int o   = tid & 7;
    const int row = blockIdx.x * 32 + r;

    const float* hrow = hidden + (size_t)row * 64;
    float acc = bfh[o];
#pragma unroll
    for (int j = 0; j < 64; ++j) acc += hrow[j] * wsh[o * 64 + j];

    const int fidx = blockIdx.x * 256 + tid;

    float pv[OO];
#pragma unroll
    for (int o2 = 0; o2 < OO; ++o2) pv[o2] = Wfo[(size_t)o2 * (BB * OO) + fidx] * acc;

    __shared__ float red[4][OO];
#pragma unroll
    for (int o2 = 0; o2 < OO; ++o2) {
        float v = pv[o2];
        for (int off = 32; off > 0; off >>= 1) v += __shfl_down(v, off);
        if ((tid & 63) == 0) red[tid >> 6][o2] = v;
    }
    __syncthreads();
    if (tid < OO) {
        partials[blockIdx.x * OO + tid] =
            red[0][tid] + red[1][tid] + red[2][tid] + red[3][tid];
    }
}

__global__ void finalize_kernel(const float* __restrict__ partials,
                                const float* __restrict__ bfo,
                                float* __restrict__ out)
{
    __shared__ float s[OO];
    const int tid = threadIdx.x;
    if (tid < OO) {
        float acc = bfo[tid];
        for (int b = 0; b < 32; ++b) acc += partials[b * OO + tid];
        s[tid] = acc;
    }
    __syncthreads();
    if (tid == 0) {
        float m = s[0];
        for (int i = 1; i < OO; ++i) m = fmaxf(m, s[i]);
        float e[OO], sum = 0.0f;
        for (int i = 0; i < OO; ++i) { e[i] = expf(s[i] - m); sum += e[i]; }
        for (int i = 0; i < OO; ++i) out[i] = e[i] / sum;
    }
}

extern "C" void kernel_launch(void* const* d_in, const int* in_sizes, int n_in,
                              void* d_out, int out_size, void* d_ws, size_t ws_size,
                              hipStream_t stream) {
    const float* x     = (const float*)d_in[0];
    const float* Wih_f = (const float*)d_in[1];
    const float* Whh_f = (const float*)d_in[2];
    const float* b_f   = (const float*)d_in[3];
    const float* Wih_b = (const float*)d_in[4];
    const float* Whh_b = (const float*)d_in[5];
    const float* b_b   = (const float*)d_in[6];
    const float* Wfh   = (const float*)d_in[7];
    const float* bfh   = (const float*)d_in[8];
    const float* Wfo   = (const float*)d_in[9];
    const float* bfo   = (const float*)d_in[10];

    float* hidden   = (float*)d_ws;
    float* partials = hidden + (size_t)BB * 64;

    lstm_seq_kernel<<<2 * BB, 64, 0, stream>>>(x, Wih_f, Whh_f, b_f,
                                               Wih_b, Whh_b, b_b, hidden);
    fc_partial_kernel<<<32, 256, 0, stream>>>(hidden, Wfh, bfh, Wfo, partials);
    finalize_kernel<<<1, 64, 0, stream>>>(partials, bfo, (float*)d_out);
}

// Round 9
// 177.478 us; speedup vs baseline: 1.3262x; 1.1286x over previous
//
#include <hip/hip_runtime.h>

#define TT 512
#define BB 1024
#define FF 16
#define HH 32
#define OO 8
#define CH 16             // timesteps per x-chunk
#define NC (TT / CH)      // 32 chunks
#define NG 128            // gate rows (4*HH)

typedef _Float16 f16;
typedef f16 v2h __attribute__((ext_vector_type(2)));
typedef f16 v4h __attribute__((ext_vector_type(4)));
typedef f16 v8h __attribute__((ext_vector_type(8)));
typedef float f32x4 __attribute__((ext_vector_type(4)));
typedef int   v2i  __attribute__((ext_vector_type(2)));

__device__ __forceinline__ float rcp_fast(float x) { return __builtin_amdgcn_rcpf(x); }
// inputs PRE-SCALED by log2e (resp. 2*log2e) -> plain exp2
__device__ __forceinline__ float sigm2(float y) {
    return rcp_fast(1.0f + __builtin_amdgcn_exp2f(-y));
}
__device__ __forceinline__ float fdot2(v2h a, v2h b, float c) {
    return __builtin_amdgcn_fdot2(a, b, c, false);
}
__device__ __forceinline__ v2h i2h(int s) { return __builtin_bit_cast(v2h, s); }

// cross-half exchange WITHOUT a DS op: v_permlane32_swap_b32 (gfx950 VALU).
// swap(p,p): result0's hi half = p's lo half -> hi lanes see prod[lane-32].
__device__ __forceinline__ float xhalf_swap(float v) {
#if __has_builtin(__builtin_amdgcn_permlane32_swap)
    int pi = __float_as_int(v);
    v2i sw = __builtin_amdgcn_permlane32_swap(pi, pi, false, false);
    return __int_as_float(sw.x);
#else
    return __shfl_xor(v, 32);
#endif
}

// One wave per block, one sequence per wave (2048 blocks, 2 waves/SIMD).
// Row-split full-k: lane (hi,kk) owns gate rows r0=kk+hi*32 (i/f), r1=r0+64
// (g/o). h-part: 32 v_dot2 vs SGPR-broadcast h. x-part: per 16-step chunk a
// batch of 8 mfma_f32_16x16x32_f16 -> LDS gxb[step][gate] with XOR swizzle
// (gate-quad q of step st stored at q ^ ((st&7)<<2)): kills the 16-way
// ds_write_b128 conflict. Per-step DS ops: ONLY 2 ds_read_b32 (hoistable);
// the half-exchange uses permlane32_swap (VALU), not ds_bpermute.
__global__ __launch_bounds__(64, 2)
void lstm_seq_kernel(const float* __restrict__ x,
                     const float* __restrict__ Wih_f, const float* __restrict__ Whh_f,
                     const float* __restrict__ b_f,
                     const float* __restrict__ Wih_b, const float* __restrict__ Whh_b,
                     const float* __restrict__ b_b,
                     float* __restrict__ hidden)
{
    const int bid  = blockIdx.x;          // 0..2047
    const int dir  = bid >> 10;           // 0 = fwd, 1 = bwd
    const int bb   = bid & (BB - 1);      // batch row
    const int lane = threadIdx.x;
    const int hi   = lane >> 5;           // 0: rows {i,g}   1: rows {f,o}
    const int kk   = lane & 31;

    const float* __restrict__ Wih  = dir ? Wih_b : Wih_f;
    const float* __restrict__ Whh  = dir ? Whh_b : Whh_f;
    const float* __restrict__ bias = dir ? b_b   : b_f;

    const float LOG2E = 1.4426950408889634f;
    const float L2E2  = 2.0f * LOG2E;

    const int r0 = kk + hi * HH;      // i (hi=0) / f (hi=1)
    const int r1 = r0 + 2 * HH;       // g (hi=0) / o (hi=1)
    const float sc0 = LOG2E;
    const float sc1 = hi ? LOG2E : L2E2;
    const float pm = hi ? 1.0f : 2.0f;
    const float pa = hi ? 0.0f : -1.0f;

    // ---- recurrent weights: 2 rows x 16 h-pairs, f16, pre-scaled ----
    v2h w0h[HH / 2], w1h[HH / 2];
#pragma unroll
    for (int q = 0; q < HH / 4; ++q) {
        float4 a = ((const float4*)(Whh + r0 * HH))[q];
        w0h[2*q]   = (v2h){(f16)(a.x * sc0), (f16)(a.y * sc0)};
        w0h[2*q+1] = (v2h){(f16)(a.z * sc0), (f16)(a.w * sc0)};
        float4 b2 = ((const float4*)(Whh + r1 * HH))[q];
        w1h[2*q]   = (v2h){(f16)(b2.x * sc1), (f16)(b2.y * sc1)};
        w1h[2*q+1] = (v2h){(f16)(b2.z * sc1), (f16)(b2.w * sc1)};
    }
    const float pb0 = bias[r0] * sc0;
    const float pb1 = bias[r1] * sc1;

    // ---- MFMA A-fragments: Wih pre-scaled, 8 tiles of 16 gate rows ----
    v8h aw[8];
#pragma unroll
    for (int T = 0; T < 8; ++T) {
        v8h t = {(f16)0,(f16)0,(f16)0,(f16)0,(f16)0,(f16)0,(f16)0,(f16)0};
        if (lane < 32) {
            const int gate = T * 16 + (lane & 15);
            const float sc = (gate >= 64 && gate < 96) ? L2E2 : LOG2E;
            const float* wrow = Wih + gate * FF + (lane >> 4) * 8;
#pragma unroll
            for (int j = 0; j < 8; ++j) t[j] = (f16)(wrow[j] * sc);
        }
        aw[T] = t;
    }

    __shared__ __align__(16) f16   xsb[2 * CH * FF];   // 1 KB: x chunks (f16)
    __shared__ __align__(16) float gxb[2 * CH * NG];   // 16 KB: x-gates (f32)

    // ---- x chunk staging: lane (sl,wl) covers step sl, quarter wl ----
    const int sl = lane >> 2;
    const int wl = lane & 3;
    const int t0 = dir ? (TT - 1 - sl) : sl;
    const float* xp = x + (size_t)t0 * (BB * FF) + (size_t)bb * FF + wl * 4;
    const ptrdiff_t dstep = (dir ? -(ptrdiff_t)CH : (ptrdiff_t)CH) * (BB * FF);

    // MFMA scatter base: D col (lane&15) = step, row (lane>>4)*4+reg = gate
    const int mst = lane & 15;            // step row
    const int mq  = (lane >> 4) * 4;      // gate quad base (lanes < 32)
    const int mxr = (mst & 7) << 2;       // per-row XOR mask (bits 2..4)

    // prologue: stage chunk 0, compute gx[0], prefetch chunk 1
    {
        float4 f0 = *(const float4*)xp;
        *(v4h*)(xsb + sl * FF + wl * 4) =
            (v4h){(f16)f0.x, (f16)f0.y, (f16)f0.z, (f16)f0.w};
    }
    xp += dstep;
    __syncthreads();
    {
        v8h bx = {(f16)0,(f16)0,(f16)0,(f16)0,(f16)0,(f16)0,(f16)0,(f16)0};
        if (lane < 32)
            bx = *(const v8h*)(xsb + (lane & 15) * FF + (lane >> 4) * 8);
        float* gw = gxb + mst * NG;
#pragma unroll
        for (int T = 0; T < 8; ++T) {
            f32x4 acc = __builtin_amdgcn_mfma_f32_16x16x32_f16(
                aw[T], bx, (f32x4){0.f, 0.f, 0.f, 0.f}, 0, 0, 0);
            *(f32x4*)(gw + ((mq + T * 16) ^ mxr)) = acc;
        }
    }
    float4 nf = *(const float4*)xp;   // chunk 1
    xp += dstep;
    __syncthreads();

    float c = 0.0f, h = 0.0f;
    int hs[HH / 2];                   // packed f16 h-pairs (wave-uniform)
#pragma unroll
    for (int m = 0; m < HH / 2; ++m) hs[m] = 0;

    for (int ci = 0; ci < NC; ++ci) {
        const int bufc = ci & 1;
        if (ci + 1 < NC) {
            const int bufn = bufc ^ 1;
            // stage chunk ci+1 and compute its gx (off the critical chain)
            *(v4h*)(xsb + bufn * (CH * FF) + sl * FF + wl * 4) =
                (v4h){(f16)nf.x, (f16)nf.y, (f16)nf.z, (f16)nf.w};
            v8h bx = {(f16)0,(f16)0,(f16)0,(f16)0,(f16)0,(f16)0,(f16)0,(f16)0};
            if (lane < 32)
                bx = *(const v8h*)(xsb + bufn * (CH * FF) + (lane & 15) * FF + (lane >> 4) * 8);
            float* gw = gxb + bufn * (CH * NG) + mst * NG;
#pragma unroll
            for (int T = 0; T < 8; ++T) {
                f32x4 acc = __builtin_amdgcn_mfma_f32_16x16x32_f16(
                    aw[T], bx, (f32x4){0.f, 0.f, 0.f, 0.f}, 0, 0, 0);
                *(f32x4*)(gw + ((mq + T * 16) ^ mxr)) = acc;
            }
            if (ci + 2 < NC) { nf = *(const float4*)xp; xp += dstep; }
        }

        const float* gxc = gxb + bufc * (CH * NG);
#pragma unroll
        for (int tt = 0; tt < CH; ++tt) {
            // x-gate contributions: XOR-swizzled columns, mask is a
            // compile-time constant per tt (loop fully unrolled)
            const int xm = (tt & 7) << 2;
            const float gx0 = gxc[tt * NG + (r0 ^ xm)];
            const float gx1 = gxc[tt * NG + (r1 ^ xm)];

            // recurrent dots: two 8-deep chains per row
            float B0 = fdot2(i2h(hs[0]), w0h[0], pb0);
            float B1 = fdot2(i2h(hs[0]), w1h[0], pb1);
            float C0 = fdot2(i2h(hs[8]), w0h[8], gx0);
            float C1 = fdot2(i2h(hs[8]), w1h[8], gx1);
#pragma unroll
            for (int j = 1; j < 8; ++j) {
                B0 = fdot2(i2h(hs[j]),     w0h[j],     B0);
                B1 = fdot2(i2h(hs[j]),     w1h[j],     B1);
                C0 = fdot2(i2h(hs[8 + j]), w0h[8 + j], C0);
                C1 = fdot2(i2h(hs[8 + j]), w1h[8 + j], C1);
            }
            const float g0 = B0 + C0;   // i (lo) / f (hi)
            const float g1 = B1 + C1;   // g (lo) / o (hi)

            const float s0 = sigm2(g0);                // si (lo) / sf (hi)
            const float s1 = fmaf(sigm2(g1), pm, pa);  // tg (lo) / so (hi)
            const float prod = s0 * s1;                // si*tg on lo lanes

            // hi lanes receive lo's si*tg via VALU permlane (no DS op!)
            const float recv = xhalf_swap(prod);
            c = fmaf(s0, c, recv);                      // hi: sf*c + si*tg
            const float th = fmaf(2.0f, sigm2(L2E2 * c), -1.0f);
            h = s1 * th;                                // hi: so*tanh(c)

            // gather h (hi lanes) into wave-uniform SGPRs for next step
            const int hn = __builtin_amdgcn_mov_dpp(__float_as_int(h),
                                                    0xB1, 0xF, 0xF, true);
            auto pk = __builtin_amdgcn_cvt_pkrtz(h, __int_as_float(hn));
            const int pki = __builtin_bit_cast(int, pk);
#pragma unroll
            for (int m = 0; m < HH / 2; ++m)
                hs[m] = __builtin_amdgcn_readlane(pki, 32 + 2 * m);
        }
        __syncthreads();   // 1-wave block: orders LDS buffers across chunks
    }

    if (hi) hidden[(size_t)bb * 64 + dir * HH + kk] = h;
}

// FC1 + per-block partial of FC2. Grid: 32 blocks x 256 threads.
__global__ __launch_bounds__(256)
void fc_partial_kernel(const float* __restrict__ hidden,
                       const float* __restrict__ Wfh, const float* __restrict__ bfh,
                       const float* __restrict__ Wfo,
                       float* __restrict__ partials)
{
    __shared__ float wsh[OO * 64];
    const int tid = threadIdx.x;
    for (int i = tid; i < OO * 64; i += 256) wsh[i] = Wfh[i];
    __syncthreads();

    const int r   = tid >> 3;
    const int o   = tid & 7;
    const int row = blockIdx.x * 32 + r;

    const float* hrow = hidden + (size_t)row * 64;
    float acc = bfh[o];
#pragma unroll
    for (int j = 0; j < 64; ++j) acc += hrow[j] * wsh[o * 64 + j];

    const int fidx = blockIdx.x * 256 + tid;

    float pv[OO];
#pragma unroll
    for (int o2 = 0; o2 < OO; ++o2) pv[o2] = Wfo[(size_t)o2 * (BB * OO) + fidx] * acc;

    __shared__ float red[4][OO];
#pragma unroll
    for (int o2 = 0; o2 < OO; ++o2) {
        float v = pv[o2];
        for (int off = 32; off > 0; off >>= 1) v += __shfl_down(v, off);
        if ((tid & 63) == 0) red[tid >> 6][o2] = v;
    }
    __syncthreads();
    if (tid < OO) {
        partials[blockIdx.x * OO + tid] =
            red[0][tid] + red[1][tid] + red[2][tid] + red[3][tid];
    }
}

__global__ void finalize_kernel(const float* __restrict__ partials,
                                const float* __restrict__ bfo,
                                float* __restrict__ out)
{
    __shared__ float s[OO];
    const int tid = threadIdx.x;
    if (tid < OO) {
        float acc = bfo[tid];
        for (int b = 0; b < 32; ++b) acc += partials[b * OO + tid];
        s[tid] = acc;
    }
    __syncthreads();
    if (tid == 0) {
        float m = s[0];
        for (int i = 1; i < OO; ++i) m = fmaxf(m, s[i]);
        float e[OO], sum = 0.0f;
        for (int i = 0; i < OO; ++i) { e[i] = expf(s[i] - m); sum += e[i]; }
        for (int i = 0; i < OO; ++i) out[i] = e[i] / sum;
    }
}

extern "C" void kernel_launch(void* const* d_in, const int* in_sizes, int n_in,
                              void* d_out, int out_size, void* d_ws, size_t ws_size,
                              hipStream_t stream) {
    const float* x     = (const float*)d_in[0];
    const float* Wih_f = (const float*)d_in[1];
    const float* Whh_f = (const float*)d_in[2];
    const float* b_f   = (const float*)d_in[3];
    const float* Wih_b = (const float*)d_in[4];
    const float* Whh_b = (const float*)d_in[5];
    const float* b_b   = (const float*)d_in[6];
    const float* Wfh   = (const float*)d_in[7];
    const float* bfh   = (const float*)d_in[8];
    const float* Wfo   = (const float*)d_in[9];
    const float* bfo   = (const float*)d_in[10];

    float* hidden   = (float*)d_ws;
    float* partials = hidden + (size_t)BB * 64;

    lstm_seq_kernel<<<2 * BB, 64, 0, stream>>>(x, Wih_f, Whh_f, b_f,
                                               Wih_b, Whh_b, b_b, hidden);
    fc_partial_kernel<<<32, 256, 0, stream>>>(hidden, Wfh, bfh, Wfo, partials);
    finalize_kernel<<<1, 64, 0, stream>>>(partials, bfo, (float*)d_out);
}